// Round 7
// baseline (222.003 us; speedup 1.0000x reference)
//
#include <hip/hip_runtime.h>
#include <hip/hip_bf16.h>

#define BATCH 2048
#define KDIM  100000
#define DIM   64
#define NKB   (KDIM / 32)     // 3125 k-blocks of 32 (exact)
#define KP    8               // k-partitions == XCDs; slabs of 390/391 kb
#define TS    16              // kb per tile (2 KB per row)
#define NSS   25              // ceil(391/16) == ceil(390/16) -> uniform
#define NRT   (BATCH / 16)    // 128 row-tiles of 16 rows
#define NSL   (KP * 4)        // 32 partial slices (kp x wave)

typedef __attribute__((ext_vector_type(8))) short  short8;
typedef __attribute__((ext_vector_type(4))) float  f32x4;

__device__ __forceinline__ unsigned short f2bf(float f) {
    union { float f; unsigned int u; } v; v.f = f;
    unsigned int u = v.u;
    u += 0x7FFFu + ((u >> 16) & 1u);          // round-to-nearest-even
    return (unsigned short)(u >> 16);
}

__device__ __forceinline__ void glds16(const float* src, unsigned char* lds) {
    __builtin_amdgcn_global_load_lds(
        (const __attribute__((address_space(1))) void*)src,
        (__attribute__((address_space(3))) void*)lds, 16, 0, 0);
}

// ---- pack emb -> bf16 in MFMA-B-fragment order ----
// pB[kb*2048 + t*512 + lane*8 + j] = bf16(emb[kb*32 + (lane>>4)*8 + j][t*16 + (lane&15)])
__global__ __launch_bounds__(256)
void hashemb_pack(const float* __restrict__ emb, unsigned short* __restrict__ pB) {
    const int kb   = blockIdx.x;              // 0..NKB-1
    const int t    = threadIdx.x >> 6;        // 0..3 col-tile
    const int lane = threadIdx.x & 63;
    const int col  = t * 16 + (lane & 15);
    const int krow = kb * 32 + (lane >> 4) * 8;

    short8 w;
    #pragma unroll
    for (int j = 0; j < 8; ++j)
        w[j] = (short)f2bf(emb[(size_t)(krow + j) * DIM + col]);

    *(short8*)&pB[(size_t)kb * 2048 + t * 512 + (size_t)lane * 8] = w;
}

__global__ __launch_bounds__(256, 2)
void hashemb_matmul(const float* __restrict__ inp,
                    const unsigned short* __restrict__ pB,
                    float* __restrict__ part,     // [NSL][BATCH][DIM]
                    float* __restrict__ rsp) {    // [NSL][BATCH]
    // cooperative tile: 16 rows x 2048 B, double-buffered (64 KB/WG, 2 WG/CU)
    __shared__ __align__(1024) unsigned char smem[2][16 * 2048];

    const int tid  = threadIdx.x;
    const int lane = tid & 63;
    const int wid  = tid >> 6;                 // wave 0..3: owns kb sub-range of tile

    const int wg = blockIdx.x;                 // 0..1023
    const int kp = wg & 7;                     // == XCD (round-robin dispatch)
    const int rb = wg >> 3;                    // 0..127 row-tile

    const int cnt   = 390 + (kp < 5 ? 1 : 0);
    const int kb0   = kp * 390 + (kp < 5 ? kp : 5);
    const int kbEnd = kb0 + cnt;

    const int rowbase = rb * 16;
    const int frow = lane & 15;                // A/LDS row
    const int g    = lane >> 4;                // k-group 0..3 within a kb
    const int sw   = frow & 7;

    // staging: instr i stages LDS row rl = wid*4 + (i>>1), half h = i&1 (1 KB each,
    // 2 consecutive instrs per row -> 2 KB contiguous run per row-visit).
    // rule #21: linear LDS dest + inverse-swizzled global source + swizzled read.
    const float* srcp[8];
    int dst[8];
    #pragma unroll
    for (int i = 0; i < 8; ++i) {
        const int rl = wid * 4 + (i >> 1);
        const int h  = i & 1;
        srcp[i] = inp + (size_t)(rowbase + rl) * KDIM + h * 256 + ((lane ^ (rl & 7)) << 2);
        dst[i]  = rl * 2048 + h * 1024;
    }

    auto tb = [&](int s) {                     // clamped tile base (stays in slab)
        int b = kb0 + s * TS;
        const int m = kbEnd - TS;
        return (b > m) ? m : b;
    };
    auto issue = [&](int base, unsigned char* buf) {
        #pragma unroll
        for (int i = 0; i < 8; ++i)
            glds16(srcp[i] + (size_t)base * 32, buf + dst[i]);
    };

    f32x4 acc[4];
    #pragma unroll
    for (int t = 0; t < 4; ++t) acc[t] = (f32x4)0.0f;
    float lsum = 0.0f;

    unsigned char* cur = &smem[0][0];
    unsigned char* nxt = &smem[1][0];
    issue(tb(0), cur);                         // prologue: 8 glds in flight/wave

    const int rdb = frow * 2048 + ((((g << 1)) ^ sw) << 4);

    for (int s = 0; s < NSS; ++s) {
        const int base = tb(s);
        const int lo   = kb0 + s * TS;
        const int cw   = base + wid * 4;       // this wave's first kb of the tile

        // 1. B-fragment loads for THIS tile (L2) — before glds so vmcnt(8) covers them
        short8 Br[4][4];
        #pragma unroll
        for (int qq = 0; qq < 4; ++qq) {
            const unsigned short* bq = pB + (size_t)(cw + qq) * 2048 + (size_t)lane * 8;
            #pragma unroll
            for (int t = 0; t < 4; ++t)
                Br[qq][t] = *(const short8*)(bq + t * 512);
        }
        __builtin_amdgcn_sched_barrier(0);

        // 2. stage next tile; counted wait keeps its 8 glds in flight
        if (s + 1 < NSS) {
            issue(tb(s + 1), nxt);
            __builtin_amdgcn_sched_barrier(0);
            asm volatile("s_waitcnt vmcnt(8)" ::: "memory");
        } else {
            asm volatile("s_waitcnt vmcnt(0)" ::: "memory");
        }
        __builtin_amdgcn_s_barrier();          // tile s visible to all waves
        __builtin_amdgcn_sched_barrier(0);

        // 3. consume: wave wid handles kb cw..cw+3 (kt = wid*4+qq within tile)
        #pragma unroll
        for (int qq = 0; qq < 4; ++qq) {
            const int c = cw + qq;
            if (c >= lo && c < kbEnd) {        // wave-uniform guard
                const int off = (wid * 4 + qq) * 128 + rdb;
                const f32x4 xa = *(const f32x4*)(cur + off);
                const f32x4 xb = *(const f32x4*)(cur + (off ^ 16));
                short8 af;
                #pragma unroll
                for (int j = 0; j < 4; ++j) {
                    af[j]     = (short)f2bf(xa[j]);
                    af[4 + j] = (short)f2bf(xb[j]);
                }
                lsum += xa[0] + xa[1] + xa[2] + xa[3]
                      + xb[0] + xb[1] + xb[2] + xb[3];
                #pragma unroll
                for (int t = 0; t < 4; ++t)
                    acc[t] = __builtin_amdgcn_mfma_f32_16x16x32_bf16(af, Br[qq][t], acc[t], 0, 0, 0);
            }
        }
        __builtin_amdgcn_sched_barrier(0);
        asm volatile("s_waitcnt lgkmcnt(0)" ::: "memory");
        __builtin_amdgcn_s_barrier();          // all reads of cur done before overwrite
        __builtin_amdgcn_sched_barrier(0);

        unsigned char* tmp = cur; cur = nxt; nxt = tmp;
    }

    const int sl = kp * 4 + wid;               // partial slice 0..31

    // ---- row-sum partial: reduce over the 4 k-groups ----
    lsum += __shfl_xor(lsum, 16, 64);
    lsum += __shfl_xor(lsum, 32, 64);
    if (lane < 16) rsp[(size_t)sl * BATCH + rowbase + lane] = lsum;

    // ---- matmul partial: C/D layout col = lane&15, row = (lane>>4)*4 + j ----
    float* po = part + (size_t)sl * BATCH * DIM;
    #pragma unroll
    for (int t = 0; t < 4; ++t) {
        const int col = t * 16 + frow;
        #pragma unroll
        for (int j = 0; j < 4; ++j) {
            const int row = rowbase + g * 4 + j;
            po[(size_t)row * DIM + col] = acc[t][j];
        }
    }
}

// out[idx] = (s>0) ? sum_p part[p][idx] / s : 0   (rs-reduce fused in)
__global__ __launch_bounds__(256)
void hashemb_finalize(const float* __restrict__ part, const float* __restrict__ rsp,
                      float* __restrict__ out) {
    const int i4  = blockIdx.x * 256 + threadIdx.x;   // 128 blocks, 32768 vec4
    const int row = i4 >> 4;                          // 16 vec4 per row

    float s = 0.0f;
    #pragma unroll
    for (int p = 0; p < NSL; ++p) s += rsp[(size_t)p * BATCH + row];

    f32x4 o = (f32x4)0.0f;
    #pragma unroll
    for (int p = 0; p < NSL; ++p)
        o += *(const f32x4*)(part + (size_t)p * BATCH * DIM + (size_t)i4 * 4);

    const float inv = (s > 0.0f) ? (1.0f / s) : 0.0f;
    o *= inv;
    *(f32x4*)(out + (size_t)i4 * 4) = o;
}

extern "C" void kernel_launch(void* const* d_in, const int* in_sizes, int n_in,
                              void* d_out, int out_size, void* d_ws, size_t ws_size,
                              hipStream_t stream) {
    const float* inp = (const float*)d_in[0];
    const float* emb = (const float*)d_in[1];
    float* out = (float*)d_out;

    // ws layout (every slot overwritten every call -> no init/memset needed):
    //   rsp  : NSL x 2048 f32           @ 0         (256 KB)
    //   part : NSL x 2048 x 64 f32      @ 262144    (16.78 MB)
    //   pB   : NKB x 2048 bf16          @ 17039360  (12.8 MB)
    float* rsp  = (float*)d_ws;
    float* part = (float*)((char*)d_ws + 262144);
    unsigned short* pB = (unsigned short*)((char*)d_ws + 17039360);

    hashemb_pack<<<NKB, 256, 0, stream>>>(emb, pB);

    hashemb_matmul<<<NRT * KP, 256, 0, stream>>>(inp, pB, part, rsp);

    hashemb_finalize<<<(BATCH * DIM / 4) / 256, 256, 0, stream>>>(part, rsp, out);
}

// Round 8
// 208.227 us; speedup vs baseline: 1.0662x; 1.0662x over previous
//
#include <hip/hip_runtime.h>
#include <hip/hip_bf16.h>

#define BATCH 2048
#define KDIM  100000
#define DIM   64
#define NKB   (KDIM / 32)        // 3125 k-blocks of 32 (exact)
#define KP    16                 // k-partitions (slabs of 195/196 kb)
#define NRB   32                 // row-blocks of 64 rows (4 waves x 16)
#define SS    4                  // k-blocks per super-step (512 B per row)
#define NSS   49                 // ceil(196/4) == ceil(195/4): uniform for all kp

typedef __attribute__((ext_vector_type(8))) short  short8;
typedef __attribute__((ext_vector_type(4))) float  f32x4;

__device__ __forceinline__ unsigned short f2bf(float f) {
    union { float f; unsigned int u; } v; v.f = f;
    unsigned int u = v.u;
    u += 0x7FFFu + ((u >> 16) & 1u);          // round-to-nearest-even
    return (unsigned short)(u >> 16);
}

// A-staging load: non-temporal (CPol NT=2) -> no L3/MALL allocation for the
// single-use 819 MB input stream (L3 churn hypothesis, round 8 A/B variable)
__device__ __forceinline__ void glds16nt(const float* src, unsigned char* lds) {
    __builtin_amdgcn_global_load_lds(
        (const __attribute__((address_space(1))) void*)src,
        (__attribute__((address_space(3))) void*)lds, 16, 0, 2);
}

// ---- pack emb -> bf16 in MFMA-B-fragment order ----
// pB[((kb*4 + t)*64 + lane)*8 + j] = bf16(emb[kb*32 + (lane>>4)*8 + j][t*16 + (lane&15)])
__global__ __launch_bounds__(256)
void hashemb_pack(const float* __restrict__ emb, unsigned short* __restrict__ pB) {
    const int kb   = blockIdx.x;              // 0..NKB-1
    const int t    = threadIdx.x >> 6;        // 0..3 col-tile
    const int lane = threadIdx.x & 63;
    const int col  = t * 16 + (lane & 15);
    const int krow = kb * 32 + (lane >> 4) * 8;

    short8 w;
    #pragma unroll
    for (int j = 0; j < 8; ++j)
        w[j] = (short)f2bf(emb[(size_t)(krow + j) * DIM + col]);

    *(short8*)&pB[(((size_t)kb * 4 + t) * 64 + lane) * 8] = w;
}

__global__ __launch_bounds__(256, 2)
void hashemb_matmul(const float* __restrict__ inp,
                    const unsigned short* __restrict__ pB,
                    float* __restrict__ part,     // [KP][BATCH][DIM]
                    float* __restrict__ rsp) {    // [KP][BATCH]
    // wave-private A staging: [wave][dbuf][16 rows x 512 B]  (64 KB/WG, 2 WG/CU)
    __shared__ __align__(1024) unsigned char smem[4][2][8192];

    const int tid  = threadIdx.x;
    const int lane = tid & 63;
    const int wid  = tid >> 6;                 // wave 0..3

    // XCD-aware decode: each XCD owns 2 contiguous kp-slabs (B slice ~1.6 MB, L2-fit)
    const int wg  = blockIdx.x;                // 0..511
    const int xcd = wg & 7;
    const int pos = wg >> 3;                   // 0..63
    const int kp  = xcd * 2 + (pos >> 5);      // 0..15
    const int rb  = pos & 31;                  // 0..31

    const int cbase = NKB / KP;                // 195
    const int rem   = NKB % KP;                // 5
    const int cnt   = cbase + (kp < rem ? 1 : 0);
    const int kb0   = kp * cbase + (kp < rem ? kp : rem);
    const int kbEnd = kb0 + cnt;

    const int rowbase = rb * 64 + wid * 16;

    // staging geometry: instr i stages rows {2i, 2i+1}, 512 B each, 1 KB contiguous issue
    const int rsub = lane >> 5;                // which of the 2 rows
    const int gcol = lane & 31;                // dest 16B-granule within row
    // consume geometry (MFMA A-fragment)
    const int frow = lane & 15;                // fragment row
    const int g    = lane >> 4;                // k-group 0..3
    const int sw   = lane & 7;                 // == frow & 7, read-side XOR

    // pre-swizzled global source row pointers (rule #21: linear LDS dest,
    // inverse-swizzled source, swizzled ds_read)
    const float* srcrow[8];
    #pragma unroll
    for (int i = 0; i < 8; ++i) {
        const int r = 2 * i + rsub;
        srcrow[i] = inp + (size_t)(rowbase + r) * KDIM + ((gcol ^ (r & 7)) << 2);
    }

    unsigned char* cur = &smem[wid][0][0];
    unsigned char* nxt = &smem[wid][1][0];

    auto ssStart = [&](int s) {                // clamped super-step base (array-end safe)
        int b = kb0 + s * SS;
        return (b > NKB - SS) ? (NKB - SS) : b;
    };
    auto issue = [&](int base, unsigned char* buf) {
        #pragma unroll
        for (int i = 0; i < 8; ++i)
            glds16nt(srcrow[i] + (size_t)base * 32, buf + i * 1024);
    };

    f32x4 acc[4];
    #pragma unroll
    for (int t = 0; t < 4; ++t) acc[t] = (f32x4)0.0f;
    float lsum = 0.0f;

    issue(kb0, cur);                           // prologue: 8 glds in flight

    for (int s = 0; s < NSS; ++s) {
        const int base = ssStart(s);
        const int lo   = kb0 + s * SS;

        // 1. B-fragment prefetch for THIS step — issued BEFORE next glds so the
        //    counted vmcnt below retires {glds(s), B} and leaves glds(s+1) in flight
        short8 Br[4][4];
        #pragma unroll
        for (int q = 0; q < SS; ++q) {
            const unsigned short* bq = pB + (size_t)(base + q) * 2048 + (size_t)lane * 8;
            #pragma unroll
            for (int t = 0; t < 4; ++t)
                Br[q][t] = *(const short8*)(bq + t * 512);
        }
        __builtin_amdgcn_sched_barrier(0);

        // 2. stage next super-step into the other half
        if (s + 1 < NSS) {
            issue(ssStart(s + 1), nxt);
            asm volatile("s_waitcnt vmcnt(8)" ::: "memory");   // drain glds(s)+B, keep glds(s+1)
        } else {
            asm volatile("s_waitcnt vmcnt(0)" ::: "memory");
        }
        __builtin_amdgcn_sched_barrier(0);

        // 3. consume current buffer: swizzled ds_read_b128 + convert + MFMA
        #pragma unroll
        for (int q = 0; q < SS; ++q) {
            const int c = base + q;
            if (c >= lo && c < kbEnd) {        // block-uniform
                const int jb = (q << 3) + (g << 1);
                const f32x4 xa = *(const f32x4*)(cur + frow * 512 + (((jb    ) ^ sw) << 4));
                const f32x4 xb = *(const f32x4*)(cur + frow * 512 + (((jb + 1) ^ sw) << 4));
                short8 af;
                #pragma unroll
                for (int j = 0; j < 4; ++j) {
                    af[j]     = (short)f2bf(xa[j]);
                    af[4 + j] = (short)f2bf(xb[j]);
                }
                lsum += xa[0] + xa[1] + xa[2] + xa[3]
                      + xb[0] + xb[1] + xb[2] + xb[3];
                #pragma unroll
                for (int t = 0; t < 4; ++t)
                    acc[t] = __builtin_amdgcn_mfma_f32_16x16x32_bf16(af, Br[q][t], acc[t], 0, 0, 0);
            }
        }

        unsigned char* tmp = cur; cur = nxt; nxt = tmp;
    }

    // ---- row-sum partials: reduce over the 4 k-groups ----
    lsum += __shfl_xor(lsum, 16, 64);
    lsum += __shfl_xor(lsum, 32, 64);
    if (lane < 16) rsp[(size_t)kp * BATCH + rowbase + lane] = lsum;

    // ---- matmul partials: C/D layout col = lane&15, row = (lane>>4)*4 + j ----
    float* po = part + (size_t)kp * BATCH * DIM;
    #pragma unroll
    for (int t = 0; t < 4; ++t) {
        const int col = t * 16 + frow;
        #pragma unroll
        for (int j = 0; j < 4; ++j) {
            const int row = rowbase + g * 4 + j;
            po[(size_t)row * DIM + col] = acc[t][j];
        }
    }
}

// out[idx] = (s>0) ? sum_p part[p][idx] / s : 0   (rs-reduce fused in)
__global__ __launch_bounds__(256)
void hashemb_finalize(const float* __restrict__ part, const float* __restrict__ rsp,
                      float* __restrict__ out) {
    const int i4  = blockIdx.x * 256 + threadIdx.x;   // 128 blocks, 32768 vec4
    const int row = i4 >> 4;                          // 16 vec4 per row

    float s = 0.0f;
    #pragma unroll
    for (int p = 0; p < KP; ++p) s += rsp[(size_t)p * BATCH + row];

    f32x4 o = (f32x4)0.0f;
    #pragma unroll
    for (int p = 0; p < KP; ++p)
        o += *(const f32x4*)(part + (size_t)p * BATCH * DIM + (size_t)i4 * 4);

    const float inv = (s > 0.0f) ? (1.0f / s) : 0.0f;
    o *= inv;
    *(f32x4*)(out + (size_t)i4 * 4) = o;
}

extern "C" void kernel_launch(void* const* d_in, const int* in_sizes, int n_in,
                              void* d_out, int out_size, void* d_ws, size_t ws_size,
                              hipStream_t stream) {
    const float* inp = (const float*)d_in[0];
    const float* emb = (const float*)d_in[1];
    float* out = (float*)d_out;

    // ws layout (every slot overwritten every call -> no init/memset needed):
    //   rsp  : KP x 2048 f32            @ 0         (128 KB)
    //   part : KP x 2048 x 64 f32       @ 131072    (8.39 MB)
    //   pB   : NKB x 4 x 64 x 8 bf16    @ 8519680   (12.8 MB)
    float* rsp  = (float*)d_ws;
    float* part = (float*)((char*)d_ws + 131072);
    unsigned short* pB = (unsigned short*)((char*)d_ws + 8519680);

    hashemb_pack<<<NKB, 256, 0, stream>>>(emb, pB);

    hashemb_matmul<<<NRB * KP, 256, 0, stream>>>(inp, pB, part, rsp);

    hashemb_finalize<<<(BATCH * DIM / 4) / 256, 256, 0, stream>>>(part, rsp, out);
}

// Round 9
// 207.839 us; speedup vs baseline: 1.0681x; 1.0019x over previous
//
#include <hip/hip_runtime.h>
#include <hip/hip_bf16.h>

#define BATCH 2048
#define KDIM  100000
#define DIM   64
#define NKB   (KDIM / 32)        // 3125 k-blocks of 32 (exact)
#define KP    16                 // k-partitions (slabs of 195/196 kb)
#define NRB   32                 // row-blocks of 64 rows (4 waves x 16)
#define SS    4                  // k-blocks per super-step (512 B per row)
#define NSS   49                 // ceil(196/4) == ceil(195/4): uniform for all kp

typedef __attribute__((ext_vector_type(8))) short  short8;
typedef __attribute__((ext_vector_type(4))) float  f32x4;

__device__ __forceinline__ unsigned short f2bf(float f) {
    union { float f; unsigned int u; } v; v.f = f;
    unsigned int u = v.u;
    u += 0x7FFFu + ((u >> 16) & 1u);          // round-to-nearest-even
    return (unsigned short)(u >> 16);
}

// A-staging load: non-temporal (CPol NT) -> minimize L3/MALL churn for the
// single-use 819 MB input stream
__device__ __forceinline__ void glds16nt(const float* src, unsigned char* lds) {
    __builtin_amdgcn_global_load_lds(
        (const __attribute__((address_space(1))) void*)src,
        (__attribute__((address_space(3))) void*)lds, 16, 0, 2);
}

// ---- pack v2: emb -> bf16 in MFMA-B-fragment order, fully coalesced reads ----
// pB[((kb*4 + t)*64 + lane)*8 + j] = bf16(emb[kb*32 + (lane>>4)*8 + j][t*16 + (lane&15)])
// Read path: thread reads 8 consecutive f32 of one emb row (256 B per 8 threads,
// perfectly coalesced, zero over-fetch) -> convert -> LDS[row][col] -> transposed
// fragment-order readout -> one coalesced 16 B store per thread.
__global__ __launch_bounds__(256)
void hashemb_pack(const float* __restrict__ emb, unsigned short* __restrict__ pB) {
    __shared__ unsigned short lds[32][72];    // +8 pad

    const int kb  = blockIdx.x;               // 0..NKB-1
    const int tid = threadIdx.x;

    // coalesced read: row r = tid>>3 (0..31), cols c0 = (tid&7)*8
    {
        const int r  = tid >> 3;
        const int c0 = (tid & 7) * 8;
        const float* src = emb + (size_t)(kb * 32 + r) * DIM + c0;
        const f32x4 v0 = *(const f32x4*)(src);
        const f32x4 v1 = *(const f32x4*)(src + 4);
        #pragma unroll
        for (int j = 0; j < 4; ++j) {
            lds[r][c0 + j]     = f2bf(v0[j]);
            lds[r][c0 + 4 + j] = f2bf(v1[j]);
        }
    }
    __syncthreads();

    // fragment-order readout + coalesced 16 B store
    const int t    = tid >> 6;                // col-tile 0..3
    const int lane = tid & 63;
    const int col  = t * 16 + (lane & 15);
    const int r0   = (lane >> 4) * 8;

    short8 w;
    #pragma unroll
    for (int j = 0; j < 8; ++j)
        w[j] = (short)lds[r0 + j][col];

    *(short8*)&pB[(((size_t)kb * 4 + t) * 64 + lane) * 8] = w;
}

__global__ __launch_bounds__(256, 2)
void hashemb_matmul(const float* __restrict__ inp,
                    const unsigned short* __restrict__ pB,
                    float* __restrict__ part,     // [KP][BATCH][DIM]
                    float* __restrict__ rsp) {    // [KP][BATCH]
    // wave-private A staging: [wave][dbuf][16 rows x 512 B]  (64 KB/WG, 2 WG/CU)
    __shared__ __align__(1024) unsigned char smem[4][2][8192];

    const int tid  = threadIdx.x;
    const int lane = tid & 63;
    const int wid  = tid >> 6;                 // wave 0..3

    // XCD-aware decode: each XCD owns 2 contiguous kp-slabs (B slice ~1.6 MB, L2-fit)
    const int wg  = blockIdx.x;                // 0..511
    const int xcd = wg & 7;
    const int pos = wg >> 3;                   // 0..63
    const int kp  = xcd * 2 + (pos >> 5);      // 0..15
    const int rb  = pos & 31;                  // 0..31

    const int cbase = NKB / KP;                // 195
    const int rem   = NKB % KP;                // 5
    const int cnt   = cbase + (kp < rem ? 1 : 0);
    const int kb0   = kp * cbase + (kp < rem ? kp : rem);
    const int kbEnd = kb0 + cnt;

    const int rowbase = rb * 64 + wid * 16;

    // staging geometry: instr i stages rows {2i, 2i+1}, 512 B each, 1 KB contiguous issue
    const int rsub = lane >> 5;                // which of the 2 rows
    const int gcol = lane & 31;                // dest 16B-granule within row
    // consume geometry (MFMA A-fragment)
    const int frow = lane & 15;                // fragment row
    const int g    = lane >> 4;                // k-group 0..3
    const int sw   = lane & 7;                 // == frow & 7, read-side XOR

    // pre-swizzled global source row pointers (rule #21: linear LDS dest,
    // inverse-swizzled source, swizzled ds_read)
    const float* srcrow[8];
    #pragma unroll
    for (int i = 0; i < 8; ++i) {
        const int r = 2 * i + rsub;
        srcrow[i] = inp + (size_t)(rowbase + r) * KDIM + ((gcol ^ (r & 7)) << 2);
    }

    unsigned char* cur = &smem[wid][0][0];
    unsigned char* nxt = &smem[wid][1][0];

    auto ssStart = [&](int s) {                // clamped super-step base (array-end safe)
        int b = kb0 + s * SS;
        return (b > NKB - SS) ? (NKB - SS) : b;
    };
    auto issue = [&](int base, unsigned char* buf) {
        #pragma unroll
        for (int i = 0; i < 8; ++i)
            glds16nt(srcrow[i] + (size_t)base * 32, buf + i * 1024);
    };

    f32x4 acc[4];
    #pragma unroll
    for (int t = 0; t < 4; ++t) acc[t] = (f32x4)0.0f;
    float lsum = 0.0f;

    issue(kb0, cur);                           // prologue: 8 glds in flight

    for (int s = 0; s < NSS; ++s) {
        const int base = ssStart(s);
        const int lo   = kb0 + s * SS;

        // 1. B-fragment prefetch for THIS step — issued BEFORE next glds so the
        //    counted vmcnt below retires {glds(s), B} and leaves glds(s+1) in flight
        short8 Br[4][4];
        #pragma unroll
        for (int q = 0; q < SS; ++q) {
            const unsigned short* bq = pB + (size_t)(base + q) * 2048 + (size_t)lane * 8;
            #pragma unroll
            for (int t = 0; t < 4; ++t)
                Br[q][t] = *(const short8*)(bq + t * 512);
        }
        __builtin_amdgcn_sched_barrier(0);

        // 2. stage next super-step into the other half
        if (s + 1 < NSS) {
            issue(ssStart(s + 1), nxt);
            asm volatile("s_waitcnt vmcnt(8)" ::: "memory");   // drain glds(s)+B, keep glds(s+1)
        } else {
            asm volatile("s_waitcnt vmcnt(0)" ::: "memory");
        }
        __builtin_amdgcn_sched_barrier(0);

        // 3. consume current buffer: swizzled ds_read_b128 + convert + MFMA
        #pragma unroll
        for (int q = 0; q < SS; ++q) {
            const int c = base + q;
            if (c >= lo && c < kbEnd) {        // block-uniform
                const int jb = (q << 3) + (g << 1);
                const f32x4 xa = *(const f32x4*)(cur + frow * 512 + (((jb    ) ^ sw) << 4));
                const f32x4 xb = *(const f32x4*)(cur + frow * 512 + (((jb + 1) ^ sw) << 4));
                short8 af;
                #pragma unroll
                for (int j = 0; j < 4; ++j) {
                    af[j]     = (short)f2bf(xa[j]);
                    af[4 + j] = (short)f2bf(xb[j]);
                }
                lsum += xa[0] + xa[1] + xa[2] + xa[3]
                      + xb[0] + xb[1] + xb[2] + xb[3];
                #pragma unroll
                for (int t = 0; t < 4; ++t)
                    acc[t] = __builtin_amdgcn_mfma_f32_16x16x32_bf16(af, Br[q][t], acc[t], 0, 0, 0);
            }
        }

        unsigned char* tmp = cur; cur = nxt; nxt = tmp;
    }

    // ---- row-sum partials: reduce over the 4 k-groups ----
    lsum += __shfl_xor(lsum, 16, 64);
    lsum += __shfl_xor(lsum, 32, 64);
    if (lane < 16) rsp[(size_t)kp * BATCH + rowbase + lane] = lsum;

    // ---- matmul partials: C/D layout col = lane&15, row = (lane>>4)*4 + j ----
    float* po = part + (size_t)kp * BATCH * DIM;
    #pragma unroll
    for (int t = 0; t < 4; ++t) {
        const int col = t * 16 + frow;
        #pragma unroll
        for (int j = 0; j < 4; ++j) {
            const int row = rowbase + g * 4 + j;
            po[(size_t)row * DIM + col] = acc[t][j];
        }
    }
}

// out[idx] = (s>0) ? sum_p part[p][idx] / s : 0   (rs-reduce fused in)
__global__ __launch_bounds__(256)
void hashemb_finalize(const float* __restrict__ part, const float* __restrict__ rsp,
                      float* __restrict__ out) {
    const int i4  = blockIdx.x * 256 + threadIdx.x;   // 128 blocks, 32768 vec4
    const int row = i4 >> 4;                          // 16 vec4 per row

    float s = 0.0f;
    #pragma unroll
    for (int p = 0; p < KP; ++p) s += rsp[(size_t)p * BATCH + row];

    f32x4 o = (f32x4)0.0f;
    #pragma unroll
    for (int p = 0; p < KP; ++p)
        o += *(const f32x4*)(part + (size_t)p * BATCH * DIM + (size_t)i4 * 4);

    const float inv = (s > 0.0f) ? (1.0f / s) : 0.0f;
    o *= inv;
    *(f32x4*)(out + (size_t)i4 * 4) = o;
}

extern "C" void kernel_launch(void* const* d_in, const int* in_sizes, int n_in,
                              void* d_out, int out_size, void* d_ws, size_t ws_size,
                              hipStream_t stream) {
    const float* inp = (const float*)d_in[0];
    const float* emb = (const float*)d_in[1];
    float* out = (float*)d_out;

    // ws layout (every slot overwritten every call -> no init/memset needed):
    //   rsp  : KP x 2048 f32            @ 0         (128 KB)
    //   part : KP x 2048 x 64 f32       @ 131072    (8.39 MB)
    //   pB   : NKB x 4 x 64 x 8 bf16    @ 8519680   (12.8 MB)
    float* rsp  = (float*)d_ws;
    float* part = (float*)((char*)d_ws + 131072);
    unsigned short* pB = (unsigned short*)((char*)d_ws + 8519680);

    hashemb_pack<<<NKB, 256, 0, stream>>>(emb, pB);

    hashemb_matmul<<<NRB * KP, 256, 0, stream>>>(inp, pB, part, rsp);

    hashemb_finalize<<<(BATCH * DIM / 4) / 256, 256, 0, stream>>>(part, rsp, out);
}